// Round 11
// baseline (246.588 us; speedup 1.0000x reference)
//
#include <hip/hip_runtime.h>
#include <hip/hip_bf16.h>
#include <math.h>

// Problem constants
#define NB    2
#define CIN   256
#define CB    128
#define HH    100
#define WW    100
#define NPIX  10000       // H*W
#define NPIXP 10112       // 79*128 padded pixel rows (featTb zero-pad)
#define CH1   640         // 128 (cur) + 512 (ltrb)
#define K2    640         // final GEMM K
#define O2    256         // final GEMM M (output channels)
#define NM    40000       // 4 * NPIX  (flattened (box,border) units per n)
#define NSAMP 11          // POOL+1 samples per border

typedef __attribute__((ext_vector_type(8))) short bf16x8;   // 8 bf16 = 4 VGPR
typedef __attribute__((ext_vector_type(4))) float f32x4;    // MFMA accumulator
typedef _Float16 h2 __attribute__((ext_vector_type(2)));    // packed fp16
typedef unsigned short ushort_t;

__device__ __forceinline__ unsigned short f2bf(float f) {   // RNE f32->bf16
    unsigned u = __float_as_uint(f);
    u += 0x7FFF + ((u >> 16) & 1);
    return (unsigned short)(u >> 16);
}
__device__ __forceinline__ float bf2f(ushort_t u) {
    return __uint_as_float(((unsigned)u) << 16);
}

#define MFMA16(a, b, c) __builtin_amdgcn_mfma_f32_16x16x32_bf16((a), (b), (c), 0, 0, 0)

// ---------------------------------------------------------------------------
// prep_k: weights -> bf16. W1b[640][256] = {wcur;wltrb}. W2b[256][640] with the
// torch permute+reshape channel shuffle folded into the K index.
// ---------------------------------------------------------------------------
__global__ __launch_bounds__(256) void prep_k(const float* __restrict__ wcur,
                                              const float* __restrict__ wltrb,
                                              const float* __restrict__ wout,
                                              ushort_t* __restrict__ W1b,
                                              ushort_t* __restrict__ W2b) {
    int id = blockIdx.x * 256 + threadIdx.x;
    if (id < CH1 * CIN) {
        const int ch = id / CIN;
        const float v = (ch < CB) ? wcur[id] : wltrb[id - CB * CIN];
        W1b[id] = f2bf(v);
        return;
    }
    id -= CH1 * CIN;
    if (id < O2 * K2) {
        const int o = id / K2, k = id % K2;
        const int korig = (k < 512) ? ((k & 127) * 4 + (k >> 7)) : k;
        W2b[id] = f2bf(wout[(size_t)o * K2 + korig]);
    }
}

// ---------------------------------------------------------------------------
// featT_k: feature fp32 [n][c][pix] -> bf16 channel-last [n][pixP][256],
// rows [NPIX, NPIXP) written as zeros (so GEMM1T tail fragments are exact 0).
// ---------------------------------------------------------------------------
__global__ __launch_bounds__(256) void featT_k(const float* __restrict__ feat,
                                               ushort_t* __restrict__ featTb) {
    __shared__ float T[128][65];
    const int pix0 = blockIdx.x * 64;
    const int ch0  = blockIdx.y * 128;
    const int n    = blockIdx.z;
    const int tid  = threadIdx.x;
    {
        const int pl = tid & 63, cl0 = tid >> 6;
#pragma unroll
        for (int i = 0; i < 32; ++i) {
            const int cl = cl0 + i * 4;
            const int pix = pix0 + pl;
            T[cl][pl] = (pix < NPIX)
                ? feat[((size_t)n * CIN + ch0 + cl) * NPIX + pix] : 0.f;
        }
    }
    __syncthreads();
    const int cl = tid & 127, pl0 = tid >> 7;
#pragma unroll
    for (int j = 0; j < 32; ++j) {
        const int pp = pl0 + j * 2;
        const int pix = pix0 + pp;
        if (pix < NPIXP)
            featTb[((size_t)n * NPIXP + pix) * CIN + ch0 + cl] = f2bf(T[cl][pp]);
    }
}

// ---------------------------------------------------------------------------
// GEMM1T (MFMA bf16, NO LDS / NO BARRIERS):
//   rawT[n][pix][ch] = sum_c feat[n][pix][c] * W1[ch][c]    (bf16 store)
// Tile 128pix x 128ch, 4 waves (2pix x 2ch), per-wave 64x64 = 16 MFMA/chunk.
// A- and B-fragments are DIRECT per-lane dwordx4 global loads (featTb/W1b are
// channel-last/k-contiguous, so each lane's 8 bf16 are contiguous).
// Tail pix rows read featTb's zero-pad -> contribute exact 0 to stats.
// Epilogue: fused instance-norm sum/sumsq + atomics.
// ---------------------------------------------------------------------------
__global__ __launch_bounds__(256) void gemm1T_k(const ushort_t* __restrict__ featTb,
                                                const ushort_t* __restrict__ W1b,
                                                ushort_t* __restrict__ rawT,
                                                float* __restrict__ st) {
    const int pix0 = blockIdx.x * 128;
    const int ch0  = blockIdx.y * 128;
    const int n    = blockIdx.z;
    const int tid  = threadIdx.x;
    const int lane = tid & 63, wv = tid >> 6;
    const int wp = wv & 1, wc = wv >> 1;          // pix half / ch half
    const int l15 = lane & 15, lg = lane >> 4;

    f32x4 acc[4][4];                              // [am(pix)][bn(ch)]
#pragma unroll
    for (int am = 0; am < 4; ++am)
#pragma unroll
        for (int bn = 0; bn < 4; ++bn)
#pragma unroll
            for (int r = 0; r < 4; ++r) acc[am][bn][r] = 0.f;

    // A fragment rows: pix = pix0 + wp*64 + am*16 + l15 ; k = k0 + lg*8
    const ushort_t* Abase = featTb + ((size_t)n * NPIXP + pix0 + wp * 64 + l15) * CIN + lg * 8;
    // B fragment rows: ch  = ch0 + wc*64 + bn*16 + l15 ; k = k0 + lg*8
    const ushort_t* Wbase = W1b + (size_t)(ch0 + wc * 64 + l15) * CIN + lg * 8;

#pragma unroll
    for (int ks = 0; ks < CIN / 32; ++ks) {
        const int k0 = ks * 32;
        bf16x8 afrag[4], bfrag[4];
#pragma unroll
        for (int am = 0; am < 4; ++am)
            afrag[am] = *(const bf16x8*)(Abase + (size_t)am * 16 * CIN + k0);
#pragma unroll
        for (int bn = 0; bn < 4; ++bn)
            bfrag[bn] = *(const bf16x8*)(Wbase + (size_t)bn * 16 * CIN + k0);
#pragma unroll
        for (int am = 0; am < 4; ++am)
#pragma unroll
            for (int bn = 0; bn < 4; ++bn)
                acc[am][bn] = MFMA16(afrag[am], bfrag[bn], acc[am][bn]);
    }

    // ---- fused instance-norm stats (pad pix rows are zeros -> contribute 0) ----
#pragma unroll
    for (int bn = 0; bn < 4; ++bn) {
        float s = 0.f, q = 0.f;
#pragma unroll
        for (int am = 0; am < 4; ++am)
#pragma unroll
            for (int r = 0; r < 4; ++r) { const float v = acc[am][bn][r]; s += v; q += v * v; }
        s += __shfl_xor(s, 16); q += __shfl_xor(q, 16);
        s += __shfl_xor(s, 32); q += __shfl_xor(q, 32);
        if (lg == 0) {
            const int ch = ch0 + wc * 64 + bn * 16 + l15;
            atomicAdd(&st[(size_t)(n * CH1 + ch) * 2],     s);
            atomicAdd(&st[(size_t)(n * CH1 + ch) * 2 + 1], q);
        }
    }

    // store rawT bf16 channel-last (D: row lg*4+r = pix, col l15 = ch)
#pragma unroll
    for (int am = 0; am < 4; ++am)
#pragma unroll
        for (int r = 0; r < 4; ++r) {
            const int pix = pix0 + wp * 64 + am * 16 + lg * 4 + r;
            if (pix < NPIX) {
                ushort_t* dst = rawT + (size_t)(n * NPIX + pix) * CH1 + ch0 + wc * 64 + l15;
#pragma unroll
                for (int bn = 0; bn < 4; ++bn) dst[bn * 16] = f2bf(acc[am][bn][r]);
            }
        }
}

// ---------------------------------------------------------------------------
// stfin_k: finalize per-(n,ch) mean / rstd. MS[n*CH1+ch] = {m, rstd}.
// ---------------------------------------------------------------------------
__global__ __launch_bounds__(256) void stfin_k(const float* __restrict__ st,
                                               float2* __restrict__ MS) {
    const int ch = blockIdx.x * 256 + threadIdx.x;
    if (ch >= NB * CH1) return;
    const float sum = st[(size_t)ch * 2];
    const float sq  = st[(size_t)ch * 2 + 1];
    const float m   = sum * (1.0f / (float)NPIX);
    const float var = fmaxf(sq * (1.0f / (float)NPIX) - m * m, 0.f);
    MS[ch] = make_float2(m, 1.0f / sqrtf(var + 1e-5f));
}

// ---------------------------------------------------------------------------
// normAll_k: stream rawT, normalize+relu ALL 640 channels:
//   ch in [0,128)   -> CATb slot 4 (bf16)
//   ch in [128,640) -> Lh[n][b][pix][128] fp16 NORMALIZED (slice-major)
// ---------------------------------------------------------------------------
__global__ __launch_bounds__(256) void normAll_k(const ushort_t* __restrict__ rawT,
                                                 const float2* __restrict__ MS,
                                                 ushort_t* __restrict__ CATb,
                                                 ushort_t* __restrict__ Lh) {
    const int id = blockIdx.x * 256 + threadIdx.x;   // (n*NPIX+pix)*80 + c8grp
    if (id >= NB * NPIX * 80) return;
    const int c8 = (id % 80) * 8;
    const int np = id / 80;                          // n*NPIX + pix
    const int n = np / NPIX, pix = np % NPIX;
    const uint4 v = *(const uint4*)(rawT + (size_t)np * CH1 + c8);
    ushort_t tmp[8]; *(uint4*)tmp = v;
    const float2* msb = MS + n * CH1 + c8;
    if (c8 < 128) {
        ushort_t outv[8];
#pragma unroll
        for (int j = 0; j < 8; ++j) {
            const float2 ms = msb[j];
            const float x = (bf2f(tmp[j]) - ms.x) * ms.y;
            outv[j] = f2bf(fmaxf(x, 0.f));
        }
        *(uint4*)(CATb + ((size_t)(n * 5 + 4) * NPIX + pix) * 128 + c8) = *(uint4*)outv;
    } else {
        _Float16 outh[8];
#pragma unroll
        for (int j = 0; j < 8; ++j) {
            const float2 ms = msb[j];
            const float x = (bf2f(tmp[j]) - ms.x) * ms.y;
            outh[j] = (_Float16)fmaxf(x, 0.f);
        }
        const int b  = (c8 - 128) >> 7;
        const int cc = (c8 - 128) & 127;
        ushort_t* dst = Lh + ((size_t)((n * 4 + b) * NPIX) + pix) * 128 + cc;
        *(uint4*)dst = *(uint4*)outh;
    }
}

// ---------------------------------------------------------------------------
// coord_k: one thread per (n, m=4p+b, sample k) -> bilinear descriptor
// (packed tap offset + valid-masked weights). Bit-identical coord math.
// Slice-major layout for XCD-affine border gather.
// ---------------------------------------------------------------------------
__global__ __launch_bounds__(256) void coord_k(const float* __restrict__ boxes,
                                               int* __restrict__ OFFS,
                                               float4* __restrict__ WTS) {
    const int id = blockIdx.x * 256 + threadIdx.x;
    if (id >= NB * NM * NSAMP) return;
    const int k  = id % NSAMP;
    const int mm = id / NSAMP;              // n*NM + m
    const int m  = mm % NM;
    const int n  = mm / NM;
    const int p = m >> 2, b = m & 3;
    const float* bx = boxes + ((size_t)n * NPIX + p) * 4;
    const float x1 = bx[0], y1 = bx[1], x2 = bx[2], y2 = bx[3];
    const float bw = __fsub_rn(x2, x1), bh = __fsub_rn(y2, y1);
    const float t = __fdiv_rn((float)k, 10.0f);
    float x, y;
    if (b == 0)      { x = __fadd_rn(x1, __fmul_rn(t, bw)); y = y1; }
    else if (b == 1) { x = x1; y = __fadd_rn(y1, __fmul_rn(t, bh)); }
    else if (b == 2) { x = __fadd_rn(x1, __fmul_rn(t, bw)); y = y2; }
    else             { x = x2; y = __fadd_rn(y1, __fmul_rn(t, bh)); }
    const bool valid = (x >= -1.f) && (x <= (float)WW) && (y >= -1.f) && (y <= (float)HH);
    x = fmaxf(x, 0.f); y = fmaxf(y, 0.f);
    const float x0f = floorf(x), y0f = floorf(y);
    const bool cx = (x0f >= (float)(WW - 1));
    const bool cy = (y0f >= (float)(HH - 1));
    const int ix0 = cx ? (WW - 1) : (int)x0f;
    const int iy0 = cy ? (HH - 1) : (int)y0f;
    const int ix1 = min(ix0 + 1, WW - 1);
    const int iy1 = min(iy0 + 1, HH - 1);
    const float lx = cx ? 0.f : __fsub_rn(x, (float)ix0);
    const float ly = cy ? 0.f : __fsub_rn(y, (float)iy0);
    const float hx = 1.f - lx, hy = 1.f - ly;
    const float vf = valid ? 1.f : 0.f;
    const int dx = ix1 - ix0, dy = iy1 - iy0;
    const int did = (((n * 4 + b) * NPIX) + p) * NSAMP + k;   // slice-major
    OFFS[did] = (iy0 * WW + ix0) | (dx << 14) | (dy << 15);
    WTS[did]  = make_float4((hy * hx) * vf, (hy * lx) * vf,
                            (ly * hx) * vf, (ly * lx) * vf);
}

// ---------------------------------------------------------------------------
// borderH_k: gather from pre-normalized fp16 Lh with clang-native packed fp16
// (ext_vector _Float16: *, __builtin_elementwise_fma/max -> v_pk_*_f16).
// XCD-affine: slice s = blockIdx.x & 7 -> (n,b); 2.56 MB hot set per XCD L2.
// 16 units x 16 lanes (8 ch each, uint4 taps) per 256-thr block.
// Weighted sums in fp16 (vals >= 0, weights in [0,1]); final bf16 rounding
// dominates error. acc init 0 == reference max (all vals >= 0).
// ---------------------------------------------------------------------------
__global__ __launch_bounds__(256) void borderH_k(const int* __restrict__ OFFS,
                                                 const float4* __restrict__ WTS,
                                                 const ushort_t* __restrict__ Lh,
                                                 ushort_t* __restrict__ CATb) {
    const int s = blockIdx.x & 7;            // slice -> XCD affinity
    const int n = s >> 2, b = s & 3;
    const int u = threadIdx.x >> 4;          // unit in block: 0..15
    const int c8 = (threadIdx.x & 15) * 8;   // channel base
    const int p = (blockIdx.x >> 3) * 16 + u;
    const ushort_t* Lbase = Lh + ((size_t)(n * 4 + b) * NPIX) * 128 + c8;
    const int dbase = (((n * 4 + b) * NPIX) + p) * NSAMP;
    h2 acc0 = (h2)0, acc1 = (h2)0, acc2 = (h2)0, acc3 = (h2)0;
#pragma unroll
    for (int k = 0; k < NSAMP; ++k) {
        const int    v  = OFFS[dbase + k];
        const float4 wt = WTS[dbase + k];
        const int off = v & 0x3FFF;
        const int dxo = ((v >> 14) & 1) * 128;
        const int dyo = ((v >> 15) & 1) * (WW * 128);
        const ushort_t* t = Lbase + (size_t)off * 128;
        h2 g00[4], g01[4], g10[4], g11[4];
        *(uint4*)g00 = *(const uint4*)(t);
        *(uint4*)g01 = *(const uint4*)(t + dxo);
        *(uint4*)g10 = *(const uint4*)(t + dyo);
        *(uint4*)g11 = *(const uint4*)(t + dyo + dxo);
        const _Float16 s00 = (_Float16)wt.x, s01 = (_Float16)wt.y;
        const _Float16 s10 = (_Float16)wt.z, s11 = (_Float16)wt.w;
        const h2 w00 = (h2){s00, s00}, w01 = (h2){s01, s01};
        const h2 w10 = (h2){s10, s10}, w11 = (h2){s11, s11};
#define TAPJ(j, accv)                                                         \
        {                                                                     \
            h2 val = w00 * g00[j];                                            \
            val = __builtin_elementwise_fma(w01, g01[j], val);                \
            val = __builtin_elementwise_fma(w10, g10[j], val);                \
            val = __builtin_elementwise_fma(w11, g11[j], val);                \
            accv = __builtin_elementwise_max(accv, val);                      \
        }
        TAPJ(0, acc0) TAPJ(1, acc1) TAPJ(2, acc2) TAPJ(3, acc3)
#undef TAPJ
    }
    const int m = p * 4 + b;
    ushort_t outv[8];
    outv[0] = f2bf((float)acc0.x); outv[1] = f2bf((float)acc0.y);
    outv[2] = f2bf((float)acc1.x); outv[3] = f2bf((float)acc1.y);
    outv[4] = f2bf((float)acc2.x); outv[5] = f2bf((float)acc2.y);
    outv[6] = f2bf((float)acc3.x); outv[7] = f2bf((float)acc3.y);
    *(uint4*)(CATb + ((size_t)n * 5 * NPIX + m) * 128 + c8) = *(uint4*)outv;
}

// ---------------------------------------------------------------------------
// GEMM2 (MFMA bf16, NO LDS / NO BARRIERS): out = relu(bout + W2b x CATb).
// Block tile 64o x 128pix, K=640 in 20 chunks; fragments direct-loaded
// per-lane from W2b / CATb (channel-last). Tail pix overreads land in the
// adjacent allocated buffer; those output columns are masked on store.
// ---------------------------------------------------------------------------
__global__ __launch_bounds__(256) void gemm2_k(const ushort_t* __restrict__ W2b,
                                               const ushort_t* __restrict__ CATb,
                                               const float* __restrict__ bout,
                                               float* __restrict__ out) {
    const int pix0 = blockIdx.x * 128;
    const int o0   = blockIdx.y * 64;
    const int n    = blockIdx.z;
    const int tid  = threadIdx.x;
    const int lane = tid & 63, wv = tid >> 6;
    const int wo = wv & 1, wp = wv >> 1;
    const int l15 = lane & 15, lg = lane >> 4;

    f32x4 acc[2][4];
#pragma unroll
    for (int am = 0; am < 2; ++am)
#pragma unroll
        for (int bn = 0; bn < 4; ++bn)
#pragma unroll
            for (int r = 0; r < 4; ++r) acc[am][bn][r] = 0.f;

    const ushort_t* CATn = CATb + (size_t)n * 5 * NPIX * 128;
    // A fragment rows: o = o0 + wo*32 + am*16 + l15 ; k = k0 + lg*8
    const ushort_t* A0 = W2b + (size_t)(o0 + wo * 32 + l15) * K2 + lg * 8;
    const ushort_t* A1 = A0 + 16 * K2;
    // B fragment rows: pix = pix0 + wp*64 + bn*16 + l15 ; CAT col = c0 + lg*8
    const ushort_t* Bbase = CATn + ((size_t)(pix0 + wp * 64 + l15)) * 128 + lg * 8;

#pragma unroll
    for (int ks = 0; ks < K2 / 32; ++ks) {
        const int k0 = ks * 32;
        const int slot = k0 >> 7, c0 = k0 & 127;
        const bf16x8 af0 = *(const bf16x8*)(A0 + k0);
        const bf16x8 af1 = *(const bf16x8*)(A1 + k0);
#pragma unroll
        for (int bn = 0; bn < 4; ++bn) {
            const bf16x8 bfr = *(const bf16x8*)(Bbase
                + ((size_t)slot * NPIX + (size_t)bn * 16) * 128 + c0);
            acc[0][bn] = MFMA16(af0, bfr, acc[0][bn]);
            acc[1][bn] = MFMA16(af1, bfr, acc[1][bn]);
        }
    }

    // epilogue: bias + relu + store
    const int obase = o0 + wo * 32 + lg * 4;
#pragma unroll
    for (int am = 0; am < 2; ++am) {
        const float4 bi = *(const float4*)&bout[obase + am * 16];
#pragma unroll
        for (int bn = 0; bn < 4; ++bn) {
            const int pix = pix0 + wp * 64 + bn * 16 + l15;
            if (pix < NPIX) {
                float* dst = out + ((size_t)n * O2 + obase + am * 16) * NPIX + pix;
                dst[0 * (size_t)NPIX] = fmaxf(acc[am][bn][0] + bi.x, 0.f);
                dst[1 * (size_t)NPIX] = fmaxf(acc[am][bn][1] + bi.y, 0.f);
                dst[2 * (size_t)NPIX] = fmaxf(acc[am][bn][2] + bi.z, 0.f);
                dst[3 * (size_t)NPIX] = fmaxf(acc[am][bn][3] + bi.w, 0.f);
            }
        }
    }
}

// ---------------------------------------------------------------------------
extern "C" void kernel_launch(void* const* d_in, const int* in_sizes, int n_in,
                              void* d_out, int out_size, void* d_ws, size_t ws_size,
                              hipStream_t stream) {
    const float* feature = (const float*)d_in[0];   // [2,256,100,100]
    const float* boxes   = (const float*)d_in[1];   // [2,10000,4]
    // d_in[2] = wh (unused by the reference)
    const float* w_cur   = (const float*)d_in[3];   // [128,256]
    // d_in[4] = b_cur  (cancelled by instance norm)
    const float* w_ltrb  = (const float*)d_in[5];   // [512,256]
    // d_in[6] = b_ltrb (cancelled by instance norm)
    const float* w_out   = (const float*)d_in[7];   // [256,640]
    const float* b_out   = (const float*)d_in[8];   // [256]
    float* out = (float*)d_out;

    float* ws = (float*)d_ws;
    float*    st     = ws;                                      // 2,560 f
    float2*   MS     = (float2*)(st + NB * CH1 * 2);            // 1,280 float2
    ushort_t* featTb = (ushort_t*)(MS + NB * CH1);              // 2*10112*256 u16
    ushort_t* rawT   = featTb + (size_t)NB * NPIXP * CIN;       // 12,800,000 u16
    ushort_t* CATb   = rawT + (size_t)NB * NPIX * CH1;          // 12,800,000 u16
    ushort_t* Lh     = CATb + (size_t)NB * 5 * NPIX * 128;      // 10,240,000 u16 (fp16)
    ushort_t* W1b    = Lh + (size_t)NB * 4 * NPIX * 128;        // 163,840 u16
    ushort_t* W2b    = W1b + CH1 * CIN;                         // 163,840 u16
    int*      OFFS   = (int*)(W2b + O2 * K2);                   // 880,000 i32
    float4*   WTS    = (float4*)(OFFS + NB * NM * NSAMP);       // 880,000 f4

    (void)hipMemsetAsync(st, 0, (size_t)NB * CH1 * 2 * sizeof(float), stream);
    prep_k<<<(CH1 * CIN + O2 * K2 + 255) / 256, 256, 0, stream>>>(w_cur, w_ltrb, w_out, W1b, W2b);
    featT_k<<<dim3(NPIXP / 64, 2, NB), 256, 0, stream>>>(feature, featTb);
    gemm1T_k<<<dim3(NPIXP / 128, CH1 / 128, NB), 256, 0, stream>>>(featTb, W1b, rawT, st);
    stfin_k<<<(NB * CH1 + 255) / 256, 256, 0, stream>>>(st, MS);
    normAll_k<<<(NB * NPIX * 80 + 255) / 256, 256, 0, stream>>>(rawT, MS, CATb, Lh);
    coord_k<<<(NB * NM * NSAMP + 255) / 256, 256, 0, stream>>>(boxes, OFFS, WTS);
    borderH_k<<<NB * 4 * NPIX / 16, 256, 0, stream>>>(OFFS, WTS, Lh, CATb);
    gemm2_k<<<dim3((NPIX + 127) / 128, O2 / 64, NB), 256, 0, stream>>>(W2b, CATb, b_out, out);
}